// Round 1
// baseline (862.737 us; speedup 1.0000x reference)
//
#include <hip/hip_runtime.h>
#include <hip/hip_bf16.h>

typedef __attribute__((ext_vector_type(8))) short short8;
typedef __attribute__((ext_vector_type(4))) float floatx4;

using bf16 = __hip_bfloat16;

#define S_LEN 2048
#define DM 1024
#define NH 16
#define DH 64
#define WIN 256

// ---------- helpers ----------
__device__ __forceinline__ unsigned short f2b(float f) {
  __hip_bfloat16 h = __float2bfloat16(f);
  return *reinterpret_cast<unsigned short*>(&h);
}
__device__ __forceinline__ float2 unpack_bf2(unsigned int u) {
  float2 r;
  r.x = __uint_as_float(u << 16);
  r.y = __uint_as_float(u & 0xffff0000u);
  return r;
}
__device__ __forceinline__ void unpack8(uint4 u, float* f) {
  float2 t;
  t = unpack_bf2(u.x); f[0] = t.x; f[1] = t.y;
  t = unpack_bf2(u.y); f[2] = t.x; f[3] = t.y;
  t = unpack_bf2(u.z); f[4] = t.x; f[5] = t.y;
  t = unpack_bf2(u.w); f[6] = t.x; f[7] = t.y;
}
__device__ __forceinline__ void lds_load16(void* lds, const void* gptr) {
  __builtin_amdgcn_global_load_lds(
      (const __attribute__((address_space(1))) unsigned int*)gptr,
      (__attribute__((address_space(3))) unsigned int*)lds, 16, 0, 0);
}

// ---------- K1: x fp32 -> bf16 ----------
__global__ __launch_bounds__(256) void k_convert_x(const float4* __restrict__ in,
                                                   ushort4* __restrict__ out) {
  int i = blockIdx.x * 256 + threadIdx.x;  // exactly 1M threads launched
  float4 v = in[i];
  ushort4 r;
  r.x = f2b(v.x); r.y = f2b(v.y); r.z = f2b(v.z); r.w = f2b(v.w);
  out[i] = r;
}

// ---------- K2: W[k][n] fp32 -> Wt[n][k] bf16 (4 matrices) ----------
__global__ __launch_bounds__(256) void k_transpose_cvt(const float* __restrict__ W0,
                                                       const float* __restrict__ W1,
                                                       const float* __restrict__ W2,
                                                       const float* __restrict__ W3,
                                                       bf16* __restrict__ out) {
  __shared__ float t[32][33];
  const float* W = (blockIdx.z == 0) ? W0 : (blockIdx.z == 1) ? W1 : (blockIdx.z == 2) ? W2 : W3;
  bf16* O = out + (size_t)blockIdx.z * 1024 * 1024;
  int x0 = blockIdx.x * 32, y0 = blockIdx.y * 32;
  int tx = threadIdx.x, ty = threadIdx.y;  // block (32,8)
  #pragma unroll
  for (int i = 0; i < 32; i += 8) t[ty + i][tx] = W[(size_t)(y0 + ty + i) * 1024 + x0 + tx];
  __syncthreads();
  #pragma unroll
  for (int i = 0; i < 32; i += 8)
    O[(size_t)(x0 + ty + i) * 1024 + y0 + tx] = __float2bfloat16(t[tx][ty + i]);
}

// ---------- K3/K5: bf16 MFMA GEMM, C = A[M][1024] * Bt[N][1024]^T ----------
// MODE 0: N=3072 (Wq|Wk|Wv), scatter to Q/K/V head layout [bh][s][64] bf16, +bias
// MODE 1: N=1024 (Wo), fp32 out [m][1024], +bias
template <int MODE>
__global__ __launch_bounds__(256) void k_gemm(const bf16* __restrict__ A,
                                              const bf16* __restrict__ Bt,
                                              const float* __restrict__ bias_q,
                                              const float* __restrict__ bias_k,
                                              const float* __restrict__ bias_v,
                                              bf16* __restrict__ Qh, bf16* __restrict__ Kh,
                                              bf16* __restrict__ Vh, float* __restrict__ outF) {
  __shared__ __align__(16) bf16 As[128 * 32];
  __shared__ __align__(16) bf16 Bs[128 * 32];
  const int tid = threadIdx.x;
  const int wave = tid >> 6, lane = tid & 63;
  const int m0 = blockIdx.y * 128, n0 = blockIdx.x * 128;
  const int r0 = tid >> 2;            // staging row 0..63
  const int cb = (tid & 3) * 16;      // staging col byte 0/16/32/48
  const char* Ag = (const char*)A + (size_t)(m0 + r0) * 2048 + cb;
  const char* Bg = (const char*)Bt + (size_t)(n0 + r0) * 2048 + cb;
  char* AsW0 = (char*)As + wave * 1024;
  char* AsW1 = (char*)As + 4096 + wave * 1024;
  char* BsW0 = (char*)Bs + wave * 1024;
  char* BsW1 = (char*)Bs + 4096 + wave * 1024;
  const int wm = (wave & 1) * 64, wn = (wave >> 1) * 64;
  const int ln = lane & 15, quad = lane >> 4;

  floatx4 acc[4][4];
  #pragma unroll
  for (int i = 0; i < 4; i++)
    #pragma unroll
    for (int j = 0; j < 4; j++) acc[i][j] = (floatx4){0.f, 0.f, 0.f, 0.f};

  for (int k0 = 0; k0 < 1024; k0 += 32) {
    __syncthreads();
    lds_load16(AsW0, Ag + k0 * 2);
    lds_load16(AsW1, Ag + 64 * 2048 + k0 * 2);
    lds_load16(BsW0, Bg + k0 * 2);
    lds_load16(BsW1, Bg + 64 * 2048 + k0 * 2);
    __syncthreads();
    short8 af[4], bfr[4];
    #pragma unroll
    for (int mi = 0; mi < 4; mi++)
      af[mi] = *(const short8*)&As[(wm + mi * 16 + ln) * 32 + quad * 8];
    #pragma unroll
    for (int ni = 0; ni < 4; ni++)
      bfr[ni] = *(const short8*)&Bs[(wn + ni * 16 + ln) * 32 + quad * 8];
    #pragma unroll
    for (int mi = 0; mi < 4; mi++)
      #pragma unroll
      for (int ni = 0; ni < 4; ni++)
        acc[mi][ni] = __builtin_amdgcn_mfma_f32_16x16x32_bf16(af[mi], bfr[ni], acc[mi][ni], 0, 0, 0);
  }

  if constexpr (MODE == 0) {
    #pragma unroll
    for (int ni = 0; ni < 4; ni++) {
      int n = n0 + wn + ni * 16 + ln;  // 0..3071
      int g = n >> 10, nn = n & 1023;
      const float* bp = (g == 0) ? bias_q : (g == 1) ? bias_k : bias_v;
      bf16* og = (g == 0) ? Qh : (g == 1) ? Kh : Vh;
      float bias = bp[nn];
      int h = nn >> 6, dd = nn & 63;
      #pragma unroll
      for (int mi = 0; mi < 4; mi++) {
        #pragma unroll
        for (int r = 0; r < 4; r++) {
          int m = m0 + wm + mi * 16 + quad * 4 + r;
          int b = m >> 11, s = m & 2047;
          og[(size_t)((b * NH + h) * S_LEN + s) * DH + dd] =
              __float2bfloat16(acc[mi][ni][r] + bias);
        }
      }
    }
  } else {
    #pragma unroll
    for (int ni = 0; ni < 4; ni++) {
      int n = n0 + wn + ni * 16 + ln;
      float bias = bias_q[n];  // bo passed in bias_q slot
      #pragma unroll
      for (int mi = 0; mi < 4; mi++)
        #pragma unroll
        for (int r = 0; r < 4; r++) {
          int m = m0 + wm + mi * 16 + quad * 4 + r;
          outF[(size_t)m * 1024 + n] = acc[mi][ni][r] + bias;
        }
    }
  }
}

// ---------- K4: banded attention, fp32 vector, online softmax ----------
// grid: B*H*(S/16) blocks of 256; each wave owns 4 queries; key chunks of 64.
__global__ __launch_bounds__(256) void k_attn(const bf16* __restrict__ Qh,
                                              const bf16* __restrict__ Kh,
                                              const bf16* __restrict__ Vh,
                                              bf16* __restrict__ aout) {
  __shared__ __align__(16) float Qs[16][64];
  __shared__ __align__(16) float Ks[64][68];   // [key][d], pad 68
  __shared__ __align__(16) float VsT[64][68];  // [d][key], pad 68
  __shared__ __align__(16) float Ps[16][64];   // [query][key]

  const int tid = threadIdx.x;
  const int wave = tid >> 6, lane = tid & 63;
  const int bh = blockIdx.x >> 7;
  const int q0 = (blockIdx.x & 127) * 16;
  const size_t base = (size_t)bh * S_LEN * DH;
  const bf16* Qp = Qh + base;
  const bf16* Kp = Kh + base;
  const bf16* Vp = Vh + base;

  {  // Q tile -> LDS fp32
    int e = tid * 4;
    int q = e >> 6, d = e & 63;
    const unsigned int* p = (const unsigned int*)(Qp + (size_t)(q0 + q) * DH + d);
    float2 a = unpack_bf2(p[0]), b = unpack_bf2(p[1]);
    Qs[q][d] = a.x; Qs[q][d + 1] = a.y; Qs[q][d + 2] = b.x; Qs[q][d + 3] = b.y;
  }

  float m_i[4], l_i[4], o_i[4];
  #pragma unroll
  for (int qi = 0; qi < 4; qi++) { m_i[qi] = -1e30f; l_i[qi] = 0.f; o_i[qi] = 0.f; }

  int cstart = q0 - WIN; if (cstart < 0) cstart = 0; cstart &= ~63;
  int cend = q0 + 16 + WIN; if (cend > S_LEN) cend = S_LEN; cend = (cend + 63) & ~63;
  if (q0 == 0) cend = S_LEN;  // global query row 0 sees everything

  const int jr = tid >> 2, db = (tid & 3) * 16;
  const int qb = wave * 4;

  int c = 0;
  while (true) {
    __syncthreads();
    {  // stage K,V chunk [c, c+64)
      const uint4* kp4 = (const uint4*)(Kp + (size_t)(c + jr) * DH + db);
      uint4 k0v = kp4[0], k1v = kp4[1];
      const uint4* vp4 = (const uint4*)(Vp + (size_t)(c + jr) * DH + db);
      uint4 v0v = vp4[0], v1v = vp4[1];
      float kf[16], vf[16];
      unpack8(k0v, kf); unpack8(k1v, kf + 8);
      unpack8(v0v, vf); unpack8(v1v, vf + 8);
      *(float4*)&Ks[jr][db + 0]  = make_float4(kf[0], kf[1], kf[2], kf[3]);
      *(float4*)&Ks[jr][db + 4]  = make_float4(kf[4], kf[5], kf[6], kf[7]);
      *(float4*)&Ks[jr][db + 8]  = make_float4(kf[8], kf[9], kf[10], kf[11]);
      *(float4*)&Ks[jr][db + 12] = make_float4(kf[12], kf[13], kf[14], kf[15]);
      #pragma unroll
      for (int u = 0; u < 16; u++) VsT[db + u][jr] = vf[u];
    }
    __syncthreads();

    // scores: lane = key (c+lane), 4 queries per wave
    float sc[4] = {0.f, 0.f, 0.f, 0.f};
    #pragma unroll
    for (int d4 = 0; d4 < 16; ++d4) {
      float4 kv = *(const float4*)&Ks[lane][d4 * 4];
      #pragma unroll
      for (int qi = 0; qi < 4; qi++) {
        float4 qv = *(const float4*)&Qs[qb + qi][d4 * 4];
        sc[qi] += kv.x * qv.x + kv.y * qv.y + kv.z * qv.z + kv.w * qv.w;
      }
    }
    const int j = c + lane;
    #pragma unroll
    for (int qi = 0; qi < 4; qi++) {
      int q = q0 + qb + qi;
      int dq = q - j;
      bool ok = (dq <= WIN && dq >= -WIN) || (q == 0) || (j == 0);
      float sv = ok ? sc[qi] * 0.125f : -1e30f;
      float mx = sv;
      #pragma unroll
      for (int off = 32; off > 0; off >>= 1) mx = fmaxf(mx, __shfl_xor(mx, off, 64));
      float mnew = fmaxf(m_i[qi], mx);
      float alpha = __expf(m_i[qi] - mnew);  // 0 on first chunk (m=-1e30)
      float p = __expf(sv - mnew);           // 0 for masked lanes
      float ps = p;
      #pragma unroll
      for (int off = 32; off > 0; off >>= 1) ps += __shfl_xor(ps, off, 64);
      l_i[qi] = l_i[qi] * alpha + ps;
      o_i[qi] *= alpha;
      m_i[qi] = mnew;
      Ps[qb + qi][lane] = p;
    }
    // PV: lane = d
    #pragma unroll
    for (int j4 = 0; j4 < 16; ++j4) {
      float4 vv = *(const float4*)&VsT[lane][j4 * 4];
      #pragma unroll
      for (int qi = 0; qi < 4; qi++) {
        float4 pp = *(const float4*)&Ps[qb + qi][j4 * 4];
        o_i[qi] += vv.x * pp.x + vv.y * pp.y + vv.z * pp.z + vv.w * pp.w;
      }
    }
    if (c == 0) { c = (cstart >= 64) ? cstart : 64; } else { c += 64; }
    if (c >= cend) break;
  }

  const int b = bh >> 4, h = bh & 15;
  #pragma unroll
  for (int qi = 0; qi < 4; qi++) {
    float inv = 1.0f / l_i[qi];
    int q = q0 + qb + qi;
    aout[(size_t)(b * S_LEN + q) * DM + h * DH + lane] = __float2bfloat16(o_i[qi] * inv);
  }
}

// ---------- launch ----------
extern "C" void kernel_launch(void* const* d_in, const int* in_sizes, int n_in,
                              void* d_out, int out_size, void* d_ws, size_t ws_size,
                              hipStream_t stream) {
  const float* x  = (const float*)d_in[0];
  const float* Wq = (const float*)d_in[1];
  const float* bq = (const float*)d_in[2];
  const float* Wk = (const float*)d_in[3];
  const float* bk = (const float*)d_in[4];
  const float* Wv = (const float*)d_in[5];
  const float* bv = (const float*)d_in[6];
  const float* Wo = (const float*)d_in[7];
  const float* bo = (const float*)d_in[8];
  float* out = (float*)d_out;

  const size_t SEG = (size_t)4096 * 1024;  // elements per 8.4MB segment
  bf16* xb = (bf16*)d_ws;
  bf16* wT = xb + SEG;        // [4][1024][1024] transposed weights
  bf16* Qh = wT + SEG;
  bf16* Kh = Qh + SEG;
  bf16* Vh = Kh + SEG;
  bf16* ao = Vh + SEG;

  k_convert_x<<<dim3(4096), dim3(256), 0, stream>>>((const float4*)x, (ushort4*)xb);
  k_transpose_cvt<<<dim3(32, 32, 4), dim3(32, 8), 0, stream>>>(Wq, Wk, Wv, Wo, wT);
  k_gemm<0><<<dim3(24, 32), dim3(256), 0, stream>>>(xb, wT, bq, bk, bv, Qh, Kh, Vh, nullptr);
  k_attn<<<dim3(4096), dim3(256), 0, stream>>>(Qh, Kh, Vh, ao);
  k_gemm<1><<<dim3(8, 32), dim3(256), 0, stream>>>(ao, wT + (size_t)3 * 1024 * 1024, bo,
                                                   nullptr, nullptr, nullptr, nullptr, nullptr, out);
}

// Round 2
// 246.254 us; speedup vs baseline: 3.5034x; 3.5034x over previous
//
#include <hip/hip_runtime.h>
#include <hip/hip_bf16.h>

typedef __attribute__((ext_vector_type(8))) short short8;
typedef __attribute__((ext_vector_type(4))) float floatx4;

using bf16 = __hip_bfloat16;

#define S_LEN 2048
#define DM 1024
#define NH 16
#define DH 64
#define WIN 256

// ---------- helpers ----------
__device__ __forceinline__ unsigned short f2b(float f) {
  __hip_bfloat16 h = __float2bfloat16(f);
  return *reinterpret_cast<unsigned short*>(&h);
}
__device__ __forceinline__ void lds_load16(void* lds, const void* gptr) {
  __builtin_amdgcn_global_load_lds(
      (const __attribute__((address_space(1))) unsigned int*)gptr,
      (__attribute__((address_space(3))) unsigned int*)lds, 16, 0, 0);
}

// ---------- K1: x fp32 -> bf16 ----------
__global__ __launch_bounds__(256) void k_convert_x(const float4* __restrict__ in,
                                                   ushort4* __restrict__ out) {
  int i = blockIdx.x * 256 + threadIdx.x;
  float4 v = in[i];
  ushort4 r;
  r.x = f2b(v.x); r.y = f2b(v.y); r.z = f2b(v.z); r.w = f2b(v.w);
  out[i] = r;
}

// ---------- K2: W[k][n] fp32 -> Wt[n][k] bf16 (4 matrices) ----------
__global__ __launch_bounds__(256) void k_transpose_cvt(const float* __restrict__ W0,
                                                       const float* __restrict__ W1,
                                                       const float* __restrict__ W2,
                                                       const float* __restrict__ W3,
                                                       bf16* __restrict__ out) {
  __shared__ float t[32][33];
  const float* W = (blockIdx.z == 0) ? W0 : (blockIdx.z == 1) ? W1 : (blockIdx.z == 2) ? W2 : W3;
  bf16* O = out + (size_t)blockIdx.z * 1024 * 1024;
  int x0 = blockIdx.x * 32, y0 = blockIdx.y * 32;
  int tx = threadIdx.x, ty = threadIdx.y;  // block (32,8)
  #pragma unroll
  for (int i = 0; i < 32; i += 8) t[ty + i][tx] = W[(size_t)(y0 + ty + i) * 1024 + x0 + tx];
  __syncthreads();
  #pragma unroll
  for (int i = 0; i < 32; i += 8)
    O[(size_t)(x0 + ty + i) * 1024 + y0 + tx] = __float2bfloat16(t[tx][ty + i]);
}

// ---------- K3/K5: bf16 MFMA GEMM, C = A[M][1024] * Bt[N][1024]^T ----------
template <int MODE>
__global__ __launch_bounds__(256) void k_gemm(const bf16* __restrict__ A,
                                              const bf16* __restrict__ Bt,
                                              const float* __restrict__ bias_q,
                                              const float* __restrict__ bias_k,
                                              const float* __restrict__ bias_v,
                                              bf16* __restrict__ Qh, bf16* __restrict__ Kh,
                                              bf16* __restrict__ Vh, float* __restrict__ outF) {
  __shared__ __align__(16) bf16 As[128 * 32];
  __shared__ __align__(16) bf16 Bs[128 * 32];
  const int tid = threadIdx.x;
  const int wave = tid >> 6, lane = tid & 63;
  const int m0 = blockIdx.y * 128, n0 = blockIdx.x * 128;
  const int r0 = tid >> 2;
  const int cb = (tid & 3) * 16;
  const char* Ag = (const char*)A + (size_t)(m0 + r0) * 2048 + cb;
  const char* Bg = (const char*)Bt + (size_t)(n0 + r0) * 2048 + cb;
  char* AsW0 = (char*)As + wave * 1024;
  char* AsW1 = (char*)As + 4096 + wave * 1024;
  char* BsW0 = (char*)Bs + wave * 1024;
  char* BsW1 = (char*)Bs + 4096 + wave * 1024;
  const int wm = (wave & 1) * 64, wn = (wave >> 1) * 64;
  const int ln = lane & 15, quad = lane >> 4;

  floatx4 acc[4][4];
  #pragma unroll
  for (int i = 0; i < 4; i++)
    #pragma unroll
    for (int j = 0; j < 4; j++) acc[i][j] = (floatx4){0.f, 0.f, 0.f, 0.f};

  for (int k0 = 0; k0 < 1024; k0 += 32) {
    __syncthreads();
    lds_load16(AsW0, Ag + k0 * 2);
    lds_load16(AsW1, Ag + 64 * 2048 + k0 * 2);
    lds_load16(BsW0, Bg + k0 * 2);
    lds_load16(BsW1, Bg + 64 * 2048 + k0 * 2);
    __syncthreads();
    short8 af[4], bfr[4];
    #pragma unroll
    for (int mi = 0; mi < 4; mi++)
      af[mi] = *(const short8*)&As[(wm + mi * 16 + ln) * 32 + quad * 8];
    #pragma unroll
    for (int ni = 0; ni < 4; ni++)
      bfr[ni] = *(const short8*)&Bs[(wn + ni * 16 + ln) * 32 + quad * 8];
    #pragma unroll
    for (int mi = 0; mi < 4; mi++)
      #pragma unroll
      for (int ni = 0; ni < 4; ni++)
        acc[mi][ni] = __builtin_amdgcn_mfma_f32_16x16x32_bf16(af[mi], bfr[ni], acc[mi][ni], 0, 0, 0);
  }

  if constexpr (MODE == 0) {
    #pragma unroll
    for (int ni = 0; ni < 4; ni++) {
      int n = n0 + wn + ni * 16 + ln;
      int g = n >> 10, nn = n & 1023;
      const float* bp = (g == 0) ? bias_q : (g == 1) ? bias_k : bias_v;
      bf16* og = (g == 0) ? Qh : (g == 1) ? Kh : Vh;
      float bias = bp[nn];
      int h = nn >> 6, dd = nn & 63;
      #pragma unroll
      for (int mi = 0; mi < 4; mi++) {
        #pragma unroll
        for (int r = 0; r < 4; r++) {
          int m = m0 + wm + mi * 16 + quad * 4 + r;
          int b = m >> 11, s = m & 2047;
          og[(size_t)((b * NH + h) * S_LEN + s) * DH + dd] =
              __float2bfloat16(acc[mi][ni][r] + bias);
        }
      }
    }
  } else {
    #pragma unroll
    for (int ni = 0; ni < 4; ni++) {
      int n = n0 + wn + ni * 16 + ln;
      float bias = bias_q[n];
      #pragma unroll
      for (int mi = 0; mi < 4; mi++)
        #pragma unroll
        for (int r = 0; r < 4; r++) {
          int m = m0 + wm + mi * 16 + quad * 4 + r;
          outF[(size_t)m * 1024 + n] = acc[mi][ni][r] + bias;
        }
    }
  }
}

// ---------- K4: MFMA flash attention ----------
// grid (S/64, B*H); block 256 = 4 waves; wave owns 16 queries; key chunks of 64.
// LDS row stride 72 bf16 (144B, 16B-aligned) spreads b128 frag reads over all banks.
__global__ __launch_bounds__(256, 4) void k_attn(const bf16* __restrict__ Qh,
                                                 const bf16* __restrict__ Kh,
                                                 const bf16* __restrict__ Vh,
                                                 bf16* __restrict__ aout) {
  __shared__ __align__(16) unsigned short Qs[64 * 72];
  __shared__ __align__(16) unsigned short Ks[64 * 72];
  __shared__ __align__(16) unsigned short VT[64 * 72];  // [d][j]
  __shared__ __align__(16) unsigned short Ps[4 * 16 * 72];

  const int tid = threadIdx.x;
  const int w = tid >> 6, lane = tid & 63;
  const int ln = lane & 15, quad = lane >> 4;
  const int bh = blockIdx.y;
  const int q0 = blockIdx.x * 64;
  const size_t base = (size_t)bh * S_LEN * DH;
  const bf16* Qp = Qh + base;
  const bf16* Kp = Kh + base;
  const bf16* Vp = Vh + base;

  const int jr = tid >> 2;        // staging row 0..63
  const int dc = (tid & 3) * 16;  // staging col 0/16/32/48

  // ---- stage Q tile (bf16, padded rows) ----
  {
    const uint4* qp = (const uint4*)(Qp + (size_t)(q0 + jr) * DH + dc);
    uint4 a = qp[0], b = qp[1];
    *(uint4*)&Qs[jr * 72 + dc] = a;
    *(uint4*)&Qs[jr * 72 + dc + 8] = b;
  }
  __syncthreads();

  short8 aq[2];
  aq[0] = *(const short8*)&Qs[(w * 16 + ln) * 72 + quad * 8];
  aq[1] = *(const short8*)&Qs[(w * 16 + ln) * 72 + 32 + quad * 8];

  floatx4 acc[4];  // O accumulator, C-layout: [dt], col=d=dt*16+ln, row=q=quad*4+r
  #pragma unroll
  for (int dt = 0; dt < 4; dt++) acc[dt] = (floatx4){0.f, 0.f, 0.f, 0.f};
  float m_i[4], l_i[4];
  #pragma unroll
  for (int r = 0; r < 4; r++) { m_i[r] = -1e30f; l_i[r] = 0.f; }

  const int qw = q0 + w * 16;  // wave's first query

  int cstart = q0 - WIN; if (cstart < 0) cstart = 0;
  int cend = q0 + 64 + WIN; if (cend > S_LEN) cend = S_LEN;
  if (q0 == 0) cend = S_LEN;  // global query row 0 sees all keys

  int c = 0;
  while (true) {
    __syncthreads();
    // ---- stage K rows + V transposed ----
    {
      const uint4* kp = (const uint4*)(Kp + (size_t)(c + jr) * DH + dc);
      uint4 ka = kp[0], kb = kp[1];
      *(uint4*)&Ks[jr * 72 + dc] = ka;
      *(uint4*)&Ks[jr * 72 + dc + 8] = kb;
      const uint4* vp = (const uint4*)(Vp + (size_t)(c + jr) * DH + dc);
      uint4 va = vp[0], vb = vp[1];
      unsigned short vs[16];
      *(uint4*)vs = va; *(uint4*)(vs + 8) = vb;
      #pragma unroll
      for (int u = 0; u < 16; u++) VT[(dc + u) * 72 + jr] = vs[u];
    }
    __syncthreads();

    const bool rel = (c == 0) || (qw == 0) ||
                     ((c + 63 >= qw - WIN) && (c <= qw + 15 + WIN));
    if (rel) {
      // ---- S = Q K^T ----
      floatx4 s[4];
      #pragma unroll
      for (int jt = 0; jt < 4; jt++) s[jt] = (floatx4){0.f, 0.f, 0.f, 0.f};
      #pragma unroll
      for (int jt = 0; jt < 4; jt++) {
        short8 bk0 = *(const short8*)&Ks[(jt * 16 + ln) * 72 + quad * 8];
        short8 bk1 = *(const short8*)&Ks[(jt * 16 + ln) * 72 + 32 + quad * 8];
        s[jt] = __builtin_amdgcn_mfma_f32_16x16x32_bf16(aq[0], bk0, s[jt], 0, 0, 0);
        s[jt] = __builtin_amdgcn_mfma_f32_16x16x32_bf16(aq[1], bk1, s[jt], 0, 0, 0);
      }
      // ---- mask + scale (in place) ----
      const bool full_in = (c >= qw - 241) && (c <= qw + 193);
      if (full_in) {
        #pragma unroll
        for (int jt = 0; jt < 4; jt++)
          #pragma unroll
          for (int r = 0; r < 4; r++) s[jt][r] *= 0.125f;
      } else {
        #pragma unroll
        for (int jt = 0; jt < 4; jt++) {
          int j = c + jt * 16 + ln;
          #pragma unroll
          for (int r = 0; r < 4; r++) {
            int q = qw + quad * 4 + r;
            int d = q - j;
            bool ok = (d <= WIN && d >= -WIN) || (q == 0) || (j == 0);
            s[jt][r] = ok ? s[jt][r] * 0.125f : -1e30f;
          }
        }
      }
      // ---- online softmax ----
      float mx[4];
      #pragma unroll
      for (int r = 0; r < 4; r++)
        mx[r] = fmaxf(fmaxf(s[0][r], s[1][r]), fmaxf(s[2][r], s[3][r]));
      #pragma unroll
      for (int off = 1; off < 16; off <<= 1)
        #pragma unroll
        for (int r = 0; r < 4; r++) mx[r] = fmaxf(mx[r], __shfl_xor(mx[r], off, 64));
      float alpha[4];
      #pragma unroll
      for (int r = 0; r < 4; r++) {
        float mnew = fmaxf(m_i[r], mx[r]);
        alpha[r] = __expf(m_i[r] - mnew);
        m_i[r] = mnew;
      }
      float ss[4] = {0.f, 0.f, 0.f, 0.f};
      #pragma unroll
      for (int jt = 0; jt < 4; jt++)
        #pragma unroll
        for (int r = 0; r < 4; r++) {
          float pe = __expf(s[jt][r] - m_i[r]);
          unsigned short us = f2b(pe);
          Ps[(w * 16 + quad * 4 + r) * 72 + jt * 16 + ln] = us;
          ss[r] += __uint_as_float((unsigned)us << 16);  // sum what PV will use
        }
      #pragma unroll
      for (int off = 1; off < 16; off <<= 1)
        #pragma unroll
        for (int r = 0; r < 4; r++) ss[r] += __shfl_xor(ss[r], off, 64);
      #pragma unroll
      for (int r = 0; r < 4; r++) l_i[r] = l_i[r] * alpha[r] + ss[r];
      #pragma unroll
      for (int dt = 0; dt < 4; dt++)
        #pragma unroll
        for (int r = 0; r < 4; r++) acc[dt][r] *= alpha[r];
      // ---- O += P V ----
      short8 ap0 = *(const short8*)&Ps[(w * 16 + ln) * 72 + quad * 8];
      short8 ap1 = *(const short8*)&Ps[(w * 16 + ln) * 72 + 32 + quad * 8];
      #pragma unroll
      for (int dt = 0; dt < 4; dt++) {
        short8 bv0 = *(const short8*)&VT[(dt * 16 + ln) * 72 + quad * 8];
        short8 bv1 = *(const short8*)&VT[(dt * 16 + ln) * 72 + 32 + quad * 8];
        acc[dt] = __builtin_amdgcn_mfma_f32_16x16x32_bf16(ap0, bv0, acc[dt], 0, 0, 0);
        acc[dt] = __builtin_amdgcn_mfma_f32_16x16x32_bf16(ap1, bv1, acc[dt], 0, 0, 0);
      }
    }
    if (c == 0) { c = (cstart >= 64) ? cstart : 64; } else { c += 64; }
    if (c >= cend) break;
  }

  // ---- epilogue: normalize + write bf16 [b][q][h*64+d] ----
  const int b = bh >> 4, h = bh & 15;
  #pragma unroll
  for (int r = 0; r < 4; r++) {
    float inv = 1.0f / l_i[r];
    int q = q0 + w * 16 + quad * 4 + r;
    #pragma unroll
    for (int dt = 0; dt < 4; dt++) {
      aout[(size_t)(b * S_LEN + q) * DM + h * DH + dt * 16 + ln] =
          __float2bfloat16(acc[dt][r] * inv);
    }
  }
}

// ---------- launch ----------
extern "C" void kernel_launch(void* const* d_in, const int* in_sizes, int n_in,
                              void* d_out, int out_size, void* d_ws, size_t ws_size,
                              hipStream_t stream) {
  const float* x  = (const float*)d_in[0];
  const float* Wq = (const float*)d_in[1];
  const float* bq = (const float*)d_in[2];
  const float* Wk = (const float*)d_in[3];
  const float* bk = (const float*)d_in[4];
  const float* Wv = (const float*)d_in[5];
  const float* bv = (const float*)d_in[6];
  const float* Wo = (const float*)d_in[7];
  const float* bo = (const float*)d_in[8];
  float* out = (float*)d_out;

  const size_t SEG = (size_t)4096 * 1024;
  bf16* xb = (bf16*)d_ws;
  bf16* wT = xb + SEG;
  bf16* Qh = wT + SEG;
  bf16* Kh = Qh + SEG;
  bf16* Vh = Kh + SEG;
  bf16* ao = Vh + SEG;

  k_convert_x<<<dim3(4096), dim3(256), 0, stream>>>((const float4*)x, (ushort4*)xb);
  k_transpose_cvt<<<dim3(32, 32, 4), dim3(32, 8), 0, stream>>>(Wq, Wk, Wv, Wo, wT);
  k_gemm<0><<<dim3(24, 32), dim3(256), 0, stream>>>(xb, wT, bq, bk, bv, Qh, Kh, Vh, nullptr);
  k_attn<<<dim3(32, 32), dim3(256), 0, stream>>>(Qh, Kh, Vh, ao);
  k_gemm<1><<<dim3(8, 32), dim3(256), 0, stream>>>(ao, wT + (size_t)3 * 1024 * 1024, bo,
                                                   nullptr, nullptr, nullptr, nullptr, nullptr, out);
}